// Round 16
// baseline (298.611 us; speedup 1.0000x reference)
//
#include <hip/hip_runtime.h>

// VQ forward == nearest-code lookup: h = x@W^T + b;  idx = argmax_v(2 h.c_v - |c_v|^2);
// out = table[idx].  R16: R15 + ONE isolated change — wave-aggregated candidate append
// (ballot + leader atomicAdd + readfirstlane) replacing the per-lane same-address LDS
// atomicAdd in scan7's collect (k-lane same-address LDS RMW serializes k-way; early
// tiles have many hits). Semantics identical; append order irrelevant.

typedef float f32x4 __attribute__((ext_vector_type(4)));
typedef short s16x8 __attribute__((ext_vector_type(8)));
typedef short s16x4 __attribute__((ext_vector_type(4)));

#define M_TOTAL 16384
#define KDIM 768
#define DQ 256
#define NV 8192
#define MARGIN 1.5f
#define CPB 4096u                 // candidate slots per block (expected ~2600)
#define NSCAN 512u                // scan blocks (64 rowblocks x 8 splits)

// ws layout (bytes)
#define OFF_TBF   0u              // ushort[NV*DQ]       4,194,304
#define OFF_WH    4194304u        // ushort[DQ*KDIM]       393,216
#define OFF_WL    4587520u        // ushort[DQ*KDIM]       393,216
#define OFF_C2    4980736u        // float[NV]              32,768
#define OFF_M     5013504u        // uint[M_TOTAL]          65,536
#define OFF_BEST  5079040u        // u64[M_TOTAL]          131,072
#define OFF_BCNT  5210112u        // uint[NSCAN]             4,096 (padded)
#define OFF_CAND  5214208u        // uint2[NSCAN*CPB]   16,777,216
#define WS_SINGLE (OFF_CAND + NSCAN * CPB * 8u)   // 21,991,424

static __device__ inline unsigned short bf_rne(float f) {
  unsigned u = __float_as_uint(f);
  u += 0x7FFFu + ((u >> 16) & 1u);
  return (unsigned short)(u >> 16);
}
static __device__ inline unsigned short bf_tr(float f) {
  return (unsigned short)(__float_as_uint(f) >> 16);
}
static __device__ inline float bf_up(unsigned short s) {
  return __uint_as_float(((unsigned)s) << 16);
}
static __device__ inline unsigned mono(float f) {
  unsigned u = __float_as_uint(f);
  return (u & 0x80000000u) ? ~u : (u | 0x80000000u);
}
static __device__ inline float demono(unsigned k) {
  unsigned u = (k & 0x80000000u) ? (k ^ 0x80000000u) : ~k;
  return __uint_as_float(u);
}
static __device__ inline f32x4 mfma16(s16x8 a, s16x8 b, f32x4 c) {
  return __builtin_amdgcn_mfma_f32_16x16x32_bf16(a, b, c, 0, 0, 0);
}
// 16-lane max via DPP row_ror butterfly (VALU-only; row of 16 == our lm-group)
#define RORMAX(v, CTRL)                                                       \
  {                                                                           \
    int _s = __builtin_amdgcn_update_dpp(0, __float_as_int(v), CTRL, 0xF, 0xF, true); \
    (v) = fmaxf((v), __int_as_float(_s));                                     \
  }
#define RMAX16(v) { RORMAX(v, 0x121) RORMAX(v, 0x122) RORMAX(v, 0x124) RORMAX(v, 0x128) }

// ============================ prep ============================
#define PB_TBF 1024
#define PB_C2  32
#define PB_W   192
#define PB_INIT 64

__global__ __launch_bounds__(256) void prep_kernel(
    const float* __restrict__ Wm, const float* __restrict__ table,
    unsigned char* __restrict__ ws) {
  unsigned short* tbf = (unsigned short*)(ws + OFF_TBF);
  unsigned short* Wh  = (unsigned short*)(ws + OFF_WH);
  unsigned short* Wl  = (unsigned short*)(ws + OFF_WL);
  float* c2 = (float*)(ws + OFF_C2);
  unsigned* Mu = (unsigned*)(ws + OFF_M);
  unsigned long long* best = (unsigned long long*)(ws + OFF_BEST);
  const int b = blockIdx.x, t = threadIdx.x;
  if (b < PB_TBF) {
    size_t e0 = ((size_t)b * 256 + t) * 8;
    float4 f0 = *(const float4*)(table + e0);
    float4 f1 = *(const float4*)(table + e0 + 4);
    s16x8 v;
    v[0]=(short)bf_rne(f0.x); v[1]=(short)bf_rne(f0.y);
    v[2]=(short)bf_rne(f0.z); v[3]=(short)bf_rne(f0.w);
    v[4]=(short)bf_rne(f1.x); v[5]=(short)bf_rne(f1.y);
    v[6]=(short)bf_rne(f1.z); v[7]=(short)bf_rne(f1.w);
    *(s16x8*)(tbf + e0) = v;
  } else if (b < PB_TBF + PB_C2) {
    const int v = (b - PB_TBF) * 256 + t;
    const float4* row = (const float4*)(table + (size_t)v * DQ);
    float s = 0.f;
    for (int q = 0; q < 64; ++q) {
      float4 x = row[q];
      s = fmaf(x.x, x.x, s); s = fmaf(x.y, x.y, s);
      s = fmaf(x.z, x.z, s); s = fmaf(x.w, x.w, s);
    }
    c2[v] = s;
  } else if (b < PB_TBF + PB_C2 + PB_W) {
    size_t i = ((size_t)(b - PB_TBF - PB_C2) * 256 + t) * 4;
    float4 f = *(const float4*)(Wm + i);
    float fv[4] = {f.x, f.y, f.z, f.w};
    s16x4 vh, vl;
#pragma unroll
    for (int q = 0; q < 4; ++q) {
      unsigned short hi = bf_tr(fv[q]);
      vh[q] = (short)hi;
      vl[q] = (short)bf_rne(fv[q] - bf_up(hi));
    }
    *(s16x4*)(Wh + i) = vh;
    *(s16x4*)(Wl + i) = vl;
  } else {
    const int i = (b - PB_TBF - PB_C2 - PB_W) * 256 + t;
    Mu[i] = 0u;            // mono(-inf-ish): any real score beats 0
    best[i] = 0ull;
  }
}

// ============================ K1: h = x@W^T + b (3-term bf16 split MFMA) ============================
// grid 512 = 128 row-tiles x 4 col-tiles; block 256 (4 waves), tile 128 rows x 64 cols.
__global__ __launch_bounds__(256, 3) void h_gemm_kernel(
    const float* __restrict__ x, const float* __restrict__ bias,
    const unsigned char* __restrict__ ws, float* __restrict__ hout) {
  const unsigned short* Whp = (const unsigned short*)(ws + OFF_WH);
  const unsigned short* Wlp = (const unsigned short*)(ws + OFF_WL);
  __shared__ unsigned short xh[128 * 40], xl[128 * 40];   // rows x padded 32-k chunk
  __shared__ unsigned short wh[64 * 40],  wl[64 * 40];
  const int t = threadIdx.x;
  const int lane = t & 63, wid = t >> 6;
  const int g = lane >> 4, lm = lane & 15;
  const int row_tile = blockIdx.x >> 2, col_tile = blockIdx.x & 3;
  const int r_ld = t >> 1, half = t & 1;       // x staging: 128 rows x 2 halves
  const int n_ld = t >> 2, qtr = t & 3;        // W staging: 64 n x 4 quarters

  f32x4 acc[2][4];
#pragma unroll
  for (int i = 0; i < 2; ++i)
#pragma unroll
    for (int j = 0; j < 4; ++j) acc[i][j] = (f32x4)0.f;

  const float* xsrc = x + (size_t)(row_tile * 128 + r_ld) * KDIM + half * 16;
  const unsigned short* whs = Whp + (size_t)(col_tile * 64 + n_ld) * KDIM + qtr * 8;
  const unsigned short* wls = Wlp + (size_t)(col_tile * 64 + n_ld) * KDIM + qtr * 8;

  float4 px[4]; s16x8 pwh, pwl;
#pragma unroll
  for (int q = 0; q < 4; ++q) px[q] = *(const float4*)(xsrc + q * 4);
  pwh = *(const s16x8*)(whs);
  pwl = *(const s16x8*)(wls);

  for (int kc = 0; kc < KDIM / 32; ++kc) {
    __syncthreads();   // prior chunk fully consumed
    {
      float fv[16] = {px[0].x, px[0].y, px[0].z, px[0].w,
                      px[1].x, px[1].y, px[1].z, px[1].w,
                      px[2].x, px[2].y, px[2].z, px[2].w,
                      px[3].x, px[3].y, px[3].z, px[3].w};
      s16x8 vh0, vh1, vl0, vl1;
#pragma unroll
      for (int e = 0; e < 8; ++e) {
        unsigned short hi = bf_tr(fv[e]);
        vh0[e] = (short)hi; vl0[e] = (short)bf_rne(fv[e] - bf_up(hi));
      }
#pragma unroll
      for (int e = 0; e < 8; ++e) {
        unsigned short hi = bf_tr(fv[8 + e]);
        vh1[e] = (short)hi; vl1[e] = (short)bf_rne(fv[8 + e] - bf_up(hi));
      }
      const int xb = r_ld * 40 + half * 16;
      *(s16x8*)&xh[xb] = vh0; *(s16x8*)&xh[xb + 8] = vh1;
      *(s16x8*)&xl[xb] = vl0; *(s16x8*)&xl[xb + 8] = vl1;
      const int wb = n_ld * 40 + qtr * 8;
      *(s16x8*)&wh[wb] = pwh;
      *(s16x8*)&wl[wb] = pwl;
    }
    if (kc + 1 < KDIM / 32) {   // prefetch next chunk (hidden under MFMA)
      const int k0 = (kc + 1) * 32;
#pragma unroll
      for (int q = 0; q < 4; ++q) px[q] = *(const float4*)(xsrc + k0 + q * 4);
      pwh = *(const s16x8*)(whs + k0);
      pwl = *(const s16x8*)(wls + k0);
    }
    __syncthreads();   // staged chunk ready
    s16x8 ah[2], al[2], bh[4], bl[4];
#pragma unroll
    for (int fr = 0; fr < 2; ++fr) {
      const int rb2 = (wid * 32 + fr * 16 + lm) * 40 + g * 8;
      ah[fr] = *(const s16x8*)&xh[rb2];
      al[fr] = *(const s16x8*)&xl[rb2];
    }
#pragma unroll
    for (int fc = 0; fc < 4; ++fc) {
      const int cb = (fc * 16 + lm) * 40 + g * 8;
      bh[fc] = *(const s16x8*)&wh[cb];
      bl[fc] = *(const s16x8*)&wl[cb];
    }
#pragma unroll
    for (int fr = 0; fr < 2; ++fr)
#pragma unroll
      for (int fc = 0; fc < 4; ++fc) {
        acc[fr][fc] = mfma16(ah[fr], bh[fc], acc[fr][fc]);
        acc[fr][fc] = mfma16(ah[fr], bl[fc], acc[fr][fc]);
        acc[fr][fc] = mfma16(al[fr], bh[fc], acc[fr][fc]);
      }
  }
  // epilogue: + bias, store fp32 h
#pragma unroll
  for (int fc = 0; fc < 4; ++fc) {
    const int col_g = col_tile * 64 + fc * 16 + lm;
    const float bv = bias[col_g];
#pragma unroll
    for (int fr = 0; fr < 2; ++fr) {
      const int row_base = row_tile * 128 + wid * 32 + fr * 16 + g * 4;
#pragma unroll
      for (int r = 0; r < 4; ++r)
        hout[(size_t)(row_base + r) * DQ + col_g] = acc[fr][fc][r] + bv;
    }
  }
}

// ============================ K2a: single-pass scan + per-block COLLECT ============================
// grid 512 = 64 rowblocks(256 rows) x 8 splits(1024 codes); block 256 = 4 waves;
// wave = 64 rows (ah[4][8], 1 B-read : 4 MFMA). Per tile: 64 MFMA (setprio) ->
// rm update -> DPP 16-lane max EVERY tile -> wave-aggregated collect (ballot +
// single leader atomicAdd per slot).
__global__ __launch_bounds__(256, 2) void scan7_kernel(
    const float* __restrict__ h, const float* __restrict__ table,
    unsigned char* __restrict__ ws) {
  const unsigned short* tbf = (const unsigned short*)(ws + OFF_TBF);
  const float* c2 = (const float*)(ws + OFF_C2);
  unsigned* Mu = (unsigned*)(ws + OFF_M);
  unsigned long long* best = (unsigned long long*)(ws + OFF_BEST);
  unsigned* bcnt = (unsigned*)(ws + OFF_BCNT);
  uint2* cand = (uint2*)(ws + OFF_CAND) + (size_t)blockIdx.x * CPB;
  __shared__ unsigned short bt[2][32 * 256];   // 2 x 16KB, swizzled
  __shared__ unsigned lcnt;

  const int t = threadIdx.x, lane = t & 63, wid = t >> 6;
  const int g4 = lane >> 4, lm = lane & 15;
  const int rb = blockIdx.x >> 3, sp = blockIdx.x & 7;
  const int wrow = rb * 256 + wid * 64;
  const int code0 = sp * 1024;

  if (t == 0) lcnt = 0u;

  // A-frags: wave's 64 rows x K=256 (128 VGPR)
  s16x8 ah[4][8];
#pragma unroll
  for (int fr = 0; fr < 4; ++fr) {
    const float* hp = h + (size_t)(wrow + fr * 16 + lm) * DQ + g4 * 8;
#pragma unroll
    for (int ks = 0; ks < 8; ++ks) {
      float4 a0 = *(const float4*)(hp + ks * 32);
      float4 a1 = *(const float4*)(hp + ks * 32 + 4);
      s16x8 v;
      v[0]=(short)bf_tr(a0.x); v[1]=(short)bf_tr(a0.y);
      v[2]=(short)bf_tr(a0.z); v[3]=(short)bf_tr(a0.w);
      v[4]=(short)bf_tr(a1.x); v[5]=(short)bf_tr(a1.y);
      v[6]=(short)bf_tr(a1.z); v[7]=(short)bf_tr(a1.w);
      ah[fr][ks] = v;
    }
  }

  float rm[4][4];
#pragma unroll
  for (int fr = 0; fr < 4; ++fr)
#pragma unroll
    for (int r = 0; r < 4; ++r) rm[fr][r] = -3.4e38f;

  int psrc[4], pdst[4];
#pragma unroll
  for (int p = 0; p < 4; ++p) {
    const int o = p * 4096 + t * 16;
    const int code = o >> 9, gsw = (o >> 4) & 31;
    const int gsrc = gsw ^ (code & 7);
    psrc[p] = code * 256 + gsrc * 8;
    pdst[p] = p * 2048 + t * 8;
  }
  const unsigned short* sbase = tbf + (size_t)code0 * DQ;

#define STAGE(buf, tilev)                                                     \
  {                                                                           \
    const unsigned short* s0 = sbase + (size_t)(tilev) * 8192;                \
    _Pragma("unroll")                                                         \
    for (int p = 0; p < 4; ++p)                                               \
      __builtin_amdgcn_global_load_lds(                                       \
          (const unsigned int*)(s0 + psrc[p]),                                \
          (unsigned int*)&bt[buf][pdst[p]], 16, 0, 0);                        \
  }

  STAGE(0, 0);
  __syncthreads();   // drains vmcnt; buf0 ready (also publishes lcnt=0)
  int cur = 0;

  for (int tile = 0; tile < 32; ++tile) {
    if (tile + 1 < 32) STAGE(cur ^ 1, tile + 1);

    f32x4 acc[4][2];
#pragma unroll
    for (int fr = 0; fr < 4; ++fr)
#pragma unroll
      for (int fc = 0; fc < 2; ++fc) acc[fr][fc] = (f32x4)0.f;

    __builtin_amdgcn_s_setprio(1);
#pragma unroll
    for (int ks = 0; ks < 8; ++ks) {
      const int gb = ks * 4 + g4;
      const int c0 = lm,      gr0 = gb ^ (c0 & 7);
      const int c1 = 16 + lm, gr1 = gb ^ (c1 & 7);
      s16x8 b0 = *(const s16x8*)&bt[cur][c0 * 256 + gr0 * 8];
      s16x8 b1 = *(const s16x8*)&bt[cur][c1 * 256 + gr1 * 8];
#pragma unroll
      for (int fr = 0; fr < 4; ++fr) {
        acc[fr][0] = mfma16(ah[fr][ks], b0, acc[fr][0]);
        acc[fr][1] = mfma16(ah[fr][ks], b1, acc[fr][1]);
      }
    }
    __builtin_amdgcn_s_setprio(0);

    // rm update from scores (scores recomputed later from live acc; no sc array)
    const float cc0 = c2[code0 + tile * 32 + lm];
    const float cc1 = c2[code0 + tile * 32 + 16 + lm];
#pragma unroll
    for (int fr = 0; fr < 4; ++fr)
#pragma unroll
      for (int r = 0; r < 4; ++r) {
        float m0 = fmaf(2.f, acc[fr][0][r], -cc0);
        float m1 = fmaf(2.f, acc[fr][1][r], -cc1);
        rm[fr][r] = fmaxf(rm[fr][r], fmaxf(m0, m1));
      }
    // share across the 16-lane group: DPP row_ror butterfly (VALU-only), EVERY tile
#pragma unroll
    for (int fr = 0; fr < 4; ++fr)
#pragma unroll
      for (int r = 0; r < 4; ++r) RMAX16(rm[fr][r])

    // COLLECT near-records: wave-aggregated append (1 LDS atomic per hit-slot)
#pragma unroll
    for (int fc = 0; fc < 2; ++fc) {
      const unsigned code_g = (unsigned)(code0 + tile * 32 + fc * 16 + lm);
      const float cc = fc ? cc1 : cc0;
#pragma unroll
      for (int fr = 0; fr < 4; ++fr)
#pragma unroll
        for (int r = 0; r < 4; ++r) {
          const float s = fmaf(2.f, acc[fr][fc][r], -cc);
          const bool hit = (s >= rm[fr][r] - MARGIN);
          const unsigned long long mask = __ballot(hit);
          if (hit) {
            const unsigned cnt = (unsigned)__popcll(mask);
            const unsigned pre =
                (unsigned)__popcll(mask & ((1ull << lane) - 1ull));
            unsigned base = 0u;
            if (pre == 0u) base = atomicAdd(&lcnt, cnt);   // leader only
            base = __builtin_amdgcn_readfirstlane(base);   // first active = leader
            const unsigned idx = base + pre;
            const unsigned row_g = (unsigned)(wrow + fr * 16 + g4 * 4 + r);
            if (idx < CPB) {
              uint2 e;
              e.x = (row_g << 13) | code_g;
              e.y = __float_as_uint(s);
              cand[idx] = e;
            } else {   // overflow (cold): inline exact rescore, identical key
              const float4* hp4 = (const float4*)(h + (size_t)row_g * DQ);
              const float4* tp4 = (const float4*)(table + (size_t)code_g * DQ);
              float dot = 0.f;
#pragma unroll 4
              for (int q = 0; q < 64; ++q) {
                float4 a = hp4[q], bb = tp4[q];
                dot = fmaf(a.x, bb.x, dot); dot = fmaf(a.y, bb.y, dot);
                dot = fmaf(a.z, bb.z, dot); dot = fmaf(a.w, bb.w, dot);
              }
              const float sx = fmaf(2.f, dot, -c2[code_g]);
              const unsigned long long key =
                  ((unsigned long long)mono(sx) << 32) |
                  (unsigned long long)(0xFFFFFFFFu - code_g);
              atomicMax(&best[row_g], key);
            }
          }
        }
    }

    __syncthreads();
    cur ^= 1;
  }
#undef STAGE

#pragma unroll
  for (int fr = 0; fr < 4; ++fr)
#pragma unroll
    for (int r = 0; r < 4; ++r)
      if (lm == 0) atomicMax(&Mu[wrow + fr * 16 + g4 * 4 + r], mono(rm[fr][r]));

  __syncthreads();   // all appends done
  if (t == 0) bcnt[blockIdx.x] = (lcnt < CPB) ? lcnt : CPB;
}

// ============================ K2b: filtered exact rescore ============================
// block b handles region b; 16 lanes per candidate; filter by final Mu BEFORE any dot.
__global__ __launch_bounds__(256) void rescore_kernel(
    const float* __restrict__ h, const float* __restrict__ table,
    unsigned char* __restrict__ ws) {
  const float* c2 = (const float*)(ws + OFF_C2);
  const unsigned* Mu = (const unsigned*)(ws + OFF_M);
  unsigned long long* best = (unsigned long long*)(ws + OFF_BEST);
  const unsigned* bcnt = (const unsigned*)(ws + OFF_BCNT);
  const uint2* cand = (const uint2*)(ws + OFF_CAND) + (size_t)blockIdx.x * CPB;

  const unsigned count = bcnt[blockIdx.x];
  const int g = threadIdx.x & 15;
  const unsigned grp = threadIdx.x >> 4;   // 16 groups per block

  for (unsigned i = grp; i < count; i += 16) {
    const uint2 e = cand[i];
    const unsigned row = e.x >> 13, code = e.x & 8191u;
    const float sbf = __uint_as_float(e.y);
    if (sbf < demono(Mu[row]) - MARGIN) continue;   // not a contender (uniform per group)
    const float4* hp = (const float4*)(h + (size_t)row * DQ);
    const float4* tp = (const float4*)(table + (size_t)code * DQ);
    float dot = 0.f;
#pragma unroll
    for (int q = 0; q < 4; ++q) {
      float4 a = hp[g * 4 + q], b = tp[g * 4 + q];
      dot = fmaf(a.x, b.x, dot); dot = fmaf(a.y, b.y, dot);
      dot = fmaf(a.z, b.z, dot); dot = fmaf(a.w, b.w, dot);
    }
    dot += __shfl_xor(dot, 1);
    dot += __shfl_xor(dot, 2);
    dot += __shfl_xor(dot, 4);
    dot += __shfl_xor(dot, 8);
    if (g == 0) {
      const float sx = fmaf(2.f, dot, -c2[code]);
      const unsigned long long key =
          ((unsigned long long)mono(sx) << 32) |
          (unsigned long long)(0xFFFFFFFFu - code);
      atomicMax(&best[row], key);   // ties -> smaller code wins (np.argmax)
    }
  }
}

// ============================ fallback two-pass scan (R7, proven) ============================
template<int MODE>
__global__ __launch_bounds__(256, 3) void scan3_kernel(
    const float* __restrict__ h, const float* __restrict__ table,
    unsigned char* __restrict__ ws) {
  const unsigned short* tbf = (const unsigned short*)(ws + OFF_TBF);
  const float* c2 = (const float*)(ws + OFF_C2);
  unsigned* Mu = (unsigned*)(ws + OFF_M);
  unsigned long long* best = (unsigned long long*)(ws + OFF_BEST);
  __shared__ unsigned short bt[2][32 * 256];

  const int t = threadIdx.x, lane = t & 63, wid = t >> 6;
  const int g4 = lane >> 4, lm = lane & 15;
  const int rb = blockIdx.x >> 3, sp = blockIdx.x & 7;
  const int wrow = rb * 128 + wid * 32;
  const int code0 = sp * 1024;

  s16x8 ah[2][8];
#pragma unroll
  for (int fr = 0; fr < 2; ++fr) {
    const float* hp = h + (size_t)(wrow + fr * 16 + lm) * DQ + g4 * 8;
#pragma unroll
    for (int ks = 0; ks < 8; ++ks) {
      float4 a0 = *(const float4*)(hp + ks * 32);
      float4 a1 = *(const float4*)(hp + ks * 32 + 4);
      s16x8 v;
      v[0]=(short)bf_tr(a0.x); v[1]=(short)bf_tr(a0.y);
      v[2]=(short)bf_tr(a0.z); v[3]=(short)bf_tr(a0.w);
      v[4]=(short)bf_tr(a1.x); v[5]=(short)bf_tr(a1.y);
      v[6]=(short)bf_tr(a1.z); v[7]=(short)bf_tr(a1.w);
      ah[fr][ks] = v;
    }
  }

  float rm[2][4];
#pragma unroll
  for (int fr = 0; fr < 2; ++fr)
#pragma unroll
    for (int r = 0; r < 4; ++r) {
      if (MODE == 2) rm[fr][r] = -3.4e38f;
      else           rm[fr][r] = demono(Mu[wrow + fr * 16 + g4 * 4 + r]);
    }

  int psrc[4], pdst[4];
#pragma unroll
  for (int p = 0; p < 4; ++p) {
    const int o = p * 4096 + t * 16;
    const int code = o >> 9, gsw = (o >> 4) & 31;
    const int gsrc = gsw ^ (code & 7);
    psrc[p] = code * 256 + gsrc * 8;
    pdst[p] = p * 2048 + t * 8;
  }
  const unsigned short* sbase = tbf + (size_t)code0 * DQ;

#define STAGE(buf, tilev)                                                     \
  {                                                                           \
    const unsigned short* s0 = sbase + (size_t)(tilev) * 8192;                \
    _Pragma("unroll")                                                         \
    for (int p = 0; p < 4; ++p)                                               \
      __builtin_amdgcn_global_load_lds(                                       \
          (const unsigned int*)(s0 + psrc[p]),                                \
          (unsigned int*)&bt[buf][pdst[p]], 16, 0, 0);                        \
  }

  STAGE(0, 0);
  __syncthreads();
  int cur = 0;

  for (int tile = 0; tile < 32; ++tile) {
    if (tile + 1 < 32) STAGE(cur ^ 1, tile + 1);

    f32x4 acc[2][2];
#pragma unroll
    for (int fr = 0; fr < 2; ++fr)
#pragma unroll
      for (int fc = 0; fc < 2; ++fc) acc[fr][fc] = (f32x4)0.f;

#pragma unroll
    for (int ks = 0; ks < 8; ++ks) {
      const int gb = ks * 4 + g4;
      const int c0 = lm,      gr0 = gb ^ (c0 & 7);
      const int c1 = 16 + lm, gr1 = gb ^ (c1 & 7);
      s16x8 b0 = *(const s16x8*)&bt[cur][c0 * 256 + gr0 * 8];
      s16x8 b1 = *(const s16x8*)&bt[cur][c1 * 256 + gr1 * 8];
      acc[0][0] = mfma16(ah[0][ks], b0, acc[0][0]);
      acc[1][0] = mfma16(ah[1][ks], b0, acc[1][0]);
      acc[0][1] = mfma16(ah[0][ks], b1, acc[0][1]);
      acc[1][1] = mfma16(ah[1][ks], b1, acc[1][1]);
    }

#pragma unroll
    for (int fc = 0; fc < 2; ++fc) {
      const int code_g = code0 + tile * 32 + fc * 16 + lm;
      const float cc = c2[code_g];
#pragma unroll
      for (int fr = 0; fr < 2; ++fr)
#pragma unroll
        for (int r = 0; r < 4; ++r) {
          const float s = fmaf(2.f, acc[fr][fc][r], -cc);
          if (MODE == 2) {
            rm[fr][r] = fmaxf(rm[fr][r], s);
          } else {
            if (s >= rm[fr][r] - MARGIN) {
              const int row_g = wrow + fr * 16 + g4 * 4 + r;
              const float4* hp4 = (const float4*)(h + (size_t)row_g * DQ);
              const float4* tp4 = (const float4*)(table + (size_t)code_g * DQ);
              float dot = 0.f;
#pragma unroll 4
              for (int q = 0; q < 64; ++q) {
                float4 a = hp4[q], bb = tp4[q];
                dot = fmaf(a.x, bb.x, dot); dot = fmaf(a.y, bb.y, dot);
                dot = fmaf(a.z, bb.z, dot); dot = fmaf(a.w, bb.w, dot);
              }
              const float sx = fmaf(2.f, dot, -cc);
              const unsigned long long key =
                  ((unsigned long long)mono(sx) << 32) |
                  (unsigned long long)(0xFFFFFFFFu - (unsigned)code_g);
              atomicMax(&best[row_g], key);
            }
          }
        }
    }

    __syncthreads();
    cur ^= 1;
  }
#undef STAGE

  if (MODE == 2) {
#pragma unroll
    for (int fr = 0; fr < 2; ++fr)
#pragma unroll
      for (int r = 0; r < 4; ++r) {
        float v = rm[fr][r];
        v = fmaxf(v, __shfl_xor(v, 1));
        v = fmaxf(v, __shfl_xor(v, 2));
        v = fmaxf(v, __shfl_xor(v, 4));
        v = fmaxf(v, __shfl_xor(v, 8));
        if (lm == 0) atomicMax(&Mu[wrow + fr * 16 + g4 * 4 + r], mono(v));
      }
  }
}

// ============================ K4: gather ============================
// grid 1024 = 16 rows/block; 16 lanes x 64B per row.
__global__ __launch_bounds__(256) void gather_kernel(
    const float* __restrict__ table, const unsigned char* __restrict__ ws,
    float* __restrict__ out) {
  const unsigned long long* best = (const unsigned long long*)(ws + OFF_BEST);
  const int row = blockIdx.x * 16 + (threadIdx.x >> 4);
  const int part = threadIdx.x & 15;
  const unsigned code = 0xFFFFFFFFu - (unsigned)(best[row] & 0xFFFFFFFFull);
  const float4* src = (const float4*)(table + (size_t)code * DQ + part * 16);
  float4* dst = (float4*)(out + (size_t)row * DQ + part * 16);
#pragma unroll
  for (int q = 0; q < 4; ++q) dst[q] = src[q];
}

// ============================ launch ============================
extern "C" void kernel_launch(void* const* d_in, const int* in_sizes, int n_in,
                              void* d_out, int out_size, void* d_ws, size_t ws_size,
                              hipStream_t stream) {
  const float* x     = (const float*)d_in[0];
  const float* Wm    = (const float*)d_in[1];
  const float* bias  = (const float*)d_in[2];
  const float* table = (const float*)d_in[3];
  float* out = (float*)d_out;
  unsigned char* ws = (unsigned char*)d_ws;

  prep_kernel<<<PB_TBF + PB_C2 + PB_W + PB_INIT, 256, 0, stream>>>(Wm, table, ws);
  h_gemm_kernel<<<512, 256, 0, stream>>>(x, bias, ws, out);    // h lives in d_out

  if (ws_size >= WS_SINGLE) {
    scan7_kernel<<<NSCAN, 256, 0, stream>>>(out, table, ws);   // scan + collect + Mu
    rescore_kernel<<<NSCAN, 256, 0, stream>>>(out, table, ws); // filter + exact rescore
  } else {
    scan3_kernel<2><<<1024, 256, 0, stream>>>(out, table, ws); // two-pass fallback (R7)
    scan3_kernel<3><<<1024, 256, 0, stream>>>(out, table, ws);
  }

  gather_kernel<<<M_TOTAL / 16, 256, 0, stream>>>(table, ws, out);
}

// Round 17
// 284.333 us; speedup vs baseline: 1.0502x; 1.0502x over previous
//
#include <hip/hip_runtime.h>

// VQ forward == nearest-code lookup: h = x@W^T + b;  idx = argmax_v(2 h.c_v - |c_v|^2);
// out = table[idx].  FINAL (R15 revert): R11 structure + neutral setprio. R16's
// ballot-aggregated append regressed (unconditional ballot overhead on all 64
// slots/tile > per-lane LDS atomic cost on ~2600 hits). Family plateau at ~285us:
// 2-blocks/CU register cap (ah[4][8]=128 VGPR + acc + rm) leaves the per-tile serial
// tail latency-exposed; 6 perturbation probes (R12-R16) all neutral or negative.
// Pipeline: prep (table->bf16, |c|^2, W hi/lo split) -> h_gemm (3-term bf16-split MFMA,
// exact-fp32-accuracy h) -> scan (bf16 MFMA scores, running row-max, margin-collect)
// -> filtered exact-fp32 rescore (argmax == fp32 argmax guaranteed: MARGIN=1.5 >> 2x
// bf16 score error) -> gather. 2314us (R1 fp32 baseline) -> 285us, 8.1x.

typedef float f32x4 __attribute__((ext_vector_type(4)));
typedef short s16x8 __attribute__((ext_vector_type(8)));
typedef short s16x4 __attribute__((ext_vector_type(4)));

#define M_TOTAL 16384
#define KDIM 768
#define DQ 256
#define NV 8192
#define MARGIN 1.5f
#define CPB 4096u                 // candidate slots per block (expected ~2600)
#define NSCAN 512u                // scan blocks (64 rowblocks x 8 splits)

// ws layout (bytes)
#define OFF_TBF   0u              // ushort[NV*DQ]       4,194,304
#define OFF_WH    4194304u        // ushort[DQ*KDIM]       393,216
#define OFF_WL    4587520u        // ushort[DQ*KDIM]       393,216
#define OFF_C2    4980736u        // float[NV]              32,768
#define OFF_M     5013504u        // uint[M_TOTAL]          65,536
#define OFF_BEST  5079040u        // u64[M_TOTAL]          131,072
#define OFF_BCNT  5210112u        // uint[NSCAN]             4,096 (padded)
#define OFF_CAND  5214208u        // uint2[NSCAN*CPB]   16,777,216
#define WS_SINGLE (OFF_CAND + NSCAN * CPB * 8u)   // 21,991,424

static __device__ inline unsigned short bf_rne(float f) {
  unsigned u = __float_as_uint(f);
  u += 0x7FFFu + ((u >> 16) & 1u);
  return (unsigned short)(u >> 16);
}
static __device__ inline unsigned short bf_tr(float f) {
  return (unsigned short)(__float_as_uint(f) >> 16);
}
static __device__ inline float bf_up(unsigned short s) {
  return __uint_as_float(((unsigned)s) << 16);
}
static __device__ inline unsigned mono(float f) {
  unsigned u = __float_as_uint(f);
  return (u & 0x80000000u) ? ~u : (u | 0x80000000u);
}
static __device__ inline float demono(unsigned k) {
  unsigned u = (k & 0x80000000u) ? (k ^ 0x80000000u) : ~k;
  return __uint_as_float(u);
}
static __device__ inline f32x4 mfma16(s16x8 a, s16x8 b, f32x4 c) {
  return __builtin_amdgcn_mfma_f32_16x16x32_bf16(a, b, c, 0, 0, 0);
}
// 16-lane max via DPP row_ror butterfly (VALU-only; row of 16 == our lm-group)
#define RORMAX(v, CTRL)                                                       \
  {                                                                           \
    int _s = __builtin_amdgcn_update_dpp(0, __float_as_int(v), CTRL, 0xF, 0xF, true); \
    (v) = fmaxf((v), __int_as_float(_s));                                     \
  }
#define RMAX16(v) { RORMAX(v, 0x121) RORMAX(v, 0x122) RORMAX(v, 0x124) RORMAX(v, 0x128) }

// ============================ prep ============================
#define PB_TBF 1024
#define PB_C2  32
#define PB_W   192
#define PB_INIT 64

__global__ __launch_bounds__(256) void prep_kernel(
    const float* __restrict__ Wm, const float* __restrict__ table,
    unsigned char* __restrict__ ws) {
  unsigned short* tbf = (unsigned short*)(ws + OFF_TBF);
  unsigned short* Wh  = (unsigned short*)(ws + OFF_WH);
  unsigned short* Wl  = (unsigned short*)(ws + OFF_WL);
  float* c2 = (float*)(ws + OFF_C2);
  unsigned* Mu = (unsigned*)(ws + OFF_M);
  unsigned long long* best = (unsigned long long*)(ws + OFF_BEST);
  const int b = blockIdx.x, t = threadIdx.x;
  if (b < PB_TBF) {
    size_t e0 = ((size_t)b * 256 + t) * 8;
    float4 f0 = *(const float4*)(table + e0);
    float4 f1 = *(const float4*)(table + e0 + 4);
    s16x8 v;
    v[0]=(short)bf_rne(f0.x); v[1]=(short)bf_rne(f0.y);
    v[2]=(short)bf_rne(f0.z); v[3]=(short)bf_rne(f0.w);
    v[4]=(short)bf_rne(f1.x); v[5]=(short)bf_rne(f1.y);
    v[6]=(short)bf_rne(f1.z); v[7]=(short)bf_rne(f1.w);
    *(s16x8*)(tbf + e0) = v;
  } else if (b < PB_TBF + PB_C2) {
    const int v = (b - PB_TBF) * 256 + t;
    const float4* row = (const float4*)(table + (size_t)v * DQ);
    float s = 0.f;
    for (int q = 0; q < 64; ++q) {
      float4 x = row[q];
      s = fmaf(x.x, x.x, s); s = fmaf(x.y, x.y, s);
      s = fmaf(x.z, x.z, s); s = fmaf(x.w, x.w, s);
    }
    c2[v] = s;
  } else if (b < PB_TBF + PB_C2 + PB_W) {
    size_t i = ((size_t)(b - PB_TBF - PB_C2) * 256 + t) * 4;
    float4 f = *(const float4*)(Wm + i);
    float fv[4] = {f.x, f.y, f.z, f.w};
    s16x4 vh, vl;
#pragma unroll
    for (int q = 0; q < 4; ++q) {
      unsigned short hi = bf_tr(fv[q]);
      vh[q] = (short)hi;
      vl[q] = (short)bf_rne(fv[q] - bf_up(hi));
    }
    *(s16x4*)(Wh + i) = vh;
    *(s16x4*)(Wl + i) = vl;
  } else {
    const int i = (b - PB_TBF - PB_C2 - PB_W) * 256 + t;
    Mu[i] = 0u;            // mono(-inf-ish): any real score beats 0
    best[i] = 0ull;
  }
}

// ============================ K1: h = x@W^T + b (3-term bf16 split MFMA) ============================
// grid 512 = 128 row-tiles x 4 col-tiles; block 256 (4 waves), tile 128 rows x 64 cols.
__global__ __launch_bounds__(256, 3) void h_gemm_kernel(
    const float* __restrict__ x, const float* __restrict__ bias,
    const unsigned char* __restrict__ ws, float* __restrict__ hout) {
  const unsigned short* Whp = (const unsigned short*)(ws + OFF_WH);
  const unsigned short* Wlp = (const unsigned short*)(ws + OFF_WL);
  __shared__ unsigned short xh[128 * 40], xl[128 * 40];   // rows x padded 32-k chunk
  __shared__ unsigned short wh[64 * 40],  wl[64 * 40];
  const int t = threadIdx.x;
  const int lane = t & 63, wid = t >> 6;
  const int g = lane >> 4, lm = lane & 15;
  const int row_tile = blockIdx.x >> 2, col_tile = blockIdx.x & 3;
  const int r_ld = t >> 1, half = t & 1;       // x staging: 128 rows x 2 halves
  const int n_ld = t >> 2, qtr = t & 3;        // W staging: 64 n x 4 quarters

  f32x4 acc[2][4];
#pragma unroll
  for (int i = 0; i < 2; ++i)
#pragma unroll
    for (int j = 0; j < 4; ++j) acc[i][j] = (f32x4)0.f;

  const float* xsrc = x + (size_t)(row_tile * 128 + r_ld) * KDIM + half * 16;
  const unsigned short* whs = Whp + (size_t)(col_tile * 64 + n_ld) * KDIM + qtr * 8;
  const unsigned short* wls = Wlp + (size_t)(col_tile * 64 + n_ld) * KDIM + qtr * 8;

  float4 px[4]; s16x8 pwh, pwl;
#pragma unroll
  for (int q = 0; q < 4; ++q) px[q] = *(const float4*)(xsrc + q * 4);
  pwh = *(const s16x8*)(whs);
  pwl = *(const s16x8*)(wls);

  for (int kc = 0; kc < KDIM / 32; ++kc) {
    __syncthreads();   // prior chunk fully consumed
    {
      float fv[16] = {px[0].x, px[0].y, px[0].z, px[0].w,
                      px[1].x, px[1].y, px[1].z, px[1].w,
                      px[2].x, px[2].y, px[2].z, px[2].w,
                      px[3].x, px[3].y, px[3].z, px[3].w};
      s16x8 vh0, vh1, vl0, vl1;
#pragma unroll
      for (int e = 0; e < 8; ++e) {
        unsigned short hi = bf_tr(fv[e]);
        vh0[e] = (short)hi; vl0[e] = (short)bf_rne(fv[e] - bf_up(hi));
      }
#pragma unroll
      for (int e = 0; e < 8; ++e) {
        unsigned short hi = bf_tr(fv[8 + e]);
        vh1[e] = (short)hi; vl1[e] = (short)bf_rne(fv[8 + e] - bf_up(hi));
      }
      const int xb = r_ld * 40 + half * 16;
      *(s16x8*)&xh[xb] = vh0; *(s16x8*)&xh[xb + 8] = vh1;
      *(s16x8*)&xl[xb] = vl0; *(s16x8*)&xl[xb + 8] = vl1;
      const int wb = n_ld * 40 + qtr * 8;
      *(s16x8*)&wh[wb] = pwh;
      *(s16x8*)&wl[wb] = pwl;
    }
    if (kc + 1 < KDIM / 32) {   // prefetch next chunk (hidden under MFMA)
      const int k0 = (kc + 1) * 32;
#pragma unroll
      for (int q = 0; q < 4; ++q) px[q] = *(const float4*)(xsrc + k0 + q * 4);
      pwh = *(const s16x8*)(whs + k0);
      pwl = *(const s16x8*)(wls + k0);
    }
    __syncthreads();   // staged chunk ready
    s16x8 ah[2], al[2], bh[4], bl[4];
#pragma unroll
    for (int fr = 0; fr < 2; ++fr) {
      const int rb2 = (wid * 32 + fr * 16 + lm) * 40 + g * 8;
      ah[fr] = *(const s16x8*)&xh[rb2];
      al[fr] = *(const s16x8*)&xl[rb2];
    }
#pragma unroll
    for (int fc = 0; fc < 4; ++fc) {
      const int cb = (fc * 16 + lm) * 40 + g * 8;
      bh[fc] = *(const s16x8*)&wh[cb];
      bl[fc] = *(const s16x8*)&wl[cb];
    }
#pragma unroll
    for (int fr = 0; fr < 2; ++fr)
#pragma unroll
      for (int fc = 0; fc < 4; ++fc) {
        acc[fr][fc] = mfma16(ah[fr], bh[fc], acc[fr][fc]);
        acc[fr][fc] = mfma16(ah[fr], bl[fc], acc[fr][fc]);
        acc[fr][fc] = mfma16(al[fr], bh[fc], acc[fr][fc]);
      }
  }
  // epilogue: + bias, store fp32 h
#pragma unroll
  for (int fc = 0; fc < 4; ++fc) {
    const int col_g = col_tile * 64 + fc * 16 + lm;
    const float bv = bias[col_g];
#pragma unroll
    for (int fr = 0; fr < 2; ++fr) {
      const int row_base = row_tile * 128 + wid * 32 + fr * 16 + g * 4;
#pragma unroll
      for (int r = 0; r < 4; ++r)
        hout[(size_t)(row_base + r) * DQ + col_g] = acc[fr][fc][r] + bv;
    }
  }
}

// ============================ K2a: single-pass scan + per-block COLLECT ============================
// grid 512 = 64 rowblocks(256 rows) x 8 splits(1024 codes); block 256 = 4 waves;
// wave = 64 rows (ah[4][8], 1 B-read : 4 MFMA). Per tile: 64 MFMA (setprio) ->
// rm update -> DPP 16-lane max EVERY tile -> collect near-records (per-lane LDS atomic).
__global__ __launch_bounds__(256, 2) void scan7_kernel(
    const float* __restrict__ h, const float* __restrict__ table,
    unsigned char* __restrict__ ws) {
  const unsigned short* tbf = (const unsigned short*)(ws + OFF_TBF);
  const float* c2 = (const float*)(ws + OFF_C2);
  unsigned* Mu = (unsigned*)(ws + OFF_M);
  unsigned long long* best = (unsigned long long*)(ws + OFF_BEST);
  unsigned* bcnt = (unsigned*)(ws + OFF_BCNT);
  uint2* cand = (uint2*)(ws + OFF_CAND) + (size_t)blockIdx.x * CPB;
  __shared__ unsigned short bt[2][32 * 256];   // 2 x 16KB, swizzled
  __shared__ unsigned lcnt;

  const int t = threadIdx.x, lane = t & 63, wid = t >> 6;
  const int g4 = lane >> 4, lm = lane & 15;
  const int rb = blockIdx.x >> 3, sp = blockIdx.x & 7;
  const int wrow = rb * 256 + wid * 64;
  const int code0 = sp * 1024;

  if (t == 0) lcnt = 0u;

  // A-frags: wave's 64 rows x K=256 (128 VGPR)
  s16x8 ah[4][8];
#pragma unroll
  for (int fr = 0; fr < 4; ++fr) {
    const float* hp = h + (size_t)(wrow + fr * 16 + lm) * DQ + g4 * 8;
#pragma unroll
    for (int ks = 0; ks < 8; ++ks) {
      float4 a0 = *(const float4*)(hp + ks * 32);
      float4 a1 = *(const float4*)(hp + ks * 32 + 4);
      s16x8 v;
      v[0]=(short)bf_tr(a0.x); v[1]=(short)bf_tr(a0.y);
      v[2]=(short)bf_tr(a0.z); v[3]=(short)bf_tr(a0.w);
      v[4]=(short)bf_tr(a1.x); v[5]=(short)bf_tr(a1.y);
      v[6]=(short)bf_tr(a1.z); v[7]=(short)bf_tr(a1.w);
      ah[fr][ks] = v;
    }
  }

  float rm[4][4];
#pragma unroll
  for (int fr = 0; fr < 4; ++fr)
#pragma unroll
    for (int r = 0; r < 4; ++r) rm[fr][r] = -3.4e38f;

  int psrc[4], pdst[4];
#pragma unroll
  for (int p = 0; p < 4; ++p) {
    const int o = p * 4096 + t * 16;
    const int code = o >> 9, gsw = (o >> 4) & 31;
    const int gsrc = gsw ^ (code & 7);
    psrc[p] = code * 256 + gsrc * 8;
    pdst[p] = p * 2048 + t * 8;
  }
  const unsigned short* sbase = tbf + (size_t)code0 * DQ;

#define STAGE(buf, tilev)                                                     \
  {                                                                           \
    const unsigned short* s0 = sbase + (size_t)(tilev) * 8192;                \
    _Pragma("unroll")                                                         \
    for (int p = 0; p < 4; ++p)                                               \
      __builtin_amdgcn_global_load_lds(                                       \
          (const unsigned int*)(s0 + psrc[p]),                                \
          (unsigned int*)&bt[buf][pdst[p]], 16, 0, 0);                        \
  }

  STAGE(0, 0);
  __syncthreads();   // drains vmcnt; buf0 ready (also publishes lcnt=0)
  int cur = 0;

  for (int tile = 0; tile < 32; ++tile) {
    if (tile + 1 < 32) STAGE(cur ^ 1, tile + 1);

    f32x4 acc[4][2];
#pragma unroll
    for (int fr = 0; fr < 4; ++fr)
#pragma unroll
      for (int fc = 0; fc < 2; ++fc) acc[fr][fc] = (f32x4)0.f;

    __builtin_amdgcn_s_setprio(1);
#pragma unroll
    for (int ks = 0; ks < 8; ++ks) {
      const int gb = ks * 4 + g4;
      const int c0 = lm,      gr0 = gb ^ (c0 & 7);
      const int c1 = 16 + lm, gr1 = gb ^ (c1 & 7);
      s16x8 b0 = *(const s16x8*)&bt[cur][c0 * 256 + gr0 * 8];
      s16x8 b1 = *(const s16x8*)&bt[cur][c1 * 256 + gr1 * 8];
#pragma unroll
      for (int fr = 0; fr < 4; ++fr) {
        acc[fr][0] = mfma16(ah[fr][ks], b0, acc[fr][0]);
        acc[fr][1] = mfma16(ah[fr][ks], b1, acc[fr][1]);
      }
    }
    __builtin_amdgcn_s_setprio(0);

    // rm update from scores (scores recomputed later from live acc; no sc array)
    const float cc0 = c2[code0 + tile * 32 + lm];
    const float cc1 = c2[code0 + tile * 32 + 16 + lm];
#pragma unroll
    for (int fr = 0; fr < 4; ++fr)
#pragma unroll
      for (int r = 0; r < 4; ++r) {
        float m0 = fmaf(2.f, acc[fr][0][r], -cc0);
        float m1 = fmaf(2.f, acc[fr][1][r], -cc1);
        rm[fr][r] = fmaxf(rm[fr][r], fmaxf(m0, m1));
      }
    // share across the 16-lane group: DPP row_ror butterfly (VALU-only), EVERY tile
#pragma unroll
    for (int fr = 0; fr < 4; ++fr)
#pragma unroll
      for (int r = 0; r < 4; ++r) RMAX16(rm[fr][r])

    // COLLECT near-records into block-private region (LDS counter)
#pragma unroll
    for (int fc = 0; fc < 2; ++fc) {
      const unsigned code_g = (unsigned)(code0 + tile * 32 + fc * 16 + lm);
      const float cc = fc ? cc1 : cc0;
#pragma unroll
      for (int fr = 0; fr < 4; ++fr)
#pragma unroll
        for (int r = 0; r < 4; ++r) {
          const float s = fmaf(2.f, acc[fr][fc][r], -cc);
          if (s >= rm[fr][r] - MARGIN) {
            const unsigned row_g = (unsigned)(wrow + fr * 16 + g4 * 4 + r);
            const unsigned idx = atomicAdd(&lcnt, 1u);   // LDS atomic: cheap
            if (idx < CPB) {
              uint2 e;
              e.x = (row_g << 13) | code_g;
              e.y = __float_as_uint(s);
              cand[idx] = e;
            } else {   // overflow (cold): inline exact rescore, identical key
              const float4* hp4 = (const float4*)(h + (size_t)row_g * DQ);
              const float4* tp4 = (const float4*)(table + (size_t)code_g * DQ);
              float dot = 0.f;
#pragma unroll 4
              for (int q = 0; q < 64; ++q) {
                float4 a = hp4[q], bb = tp4[q];
                dot = fmaf(a.x, bb.x, dot); dot = fmaf(a.y, bb.y, dot);
                dot = fmaf(a.z, bb.z, dot); dot = fmaf(a.w, bb.w, dot);
              }
              const float sx = fmaf(2.f, dot, -c2[code_g]);
              const unsigned long long key =
                  ((unsigned long long)mono(sx) << 32) |
                  (unsigned long long)(0xFFFFFFFFu - code_g);
              atomicMax(&best[row_g], key);
            }
          }
        }
    }

    __syncthreads();
    cur ^= 1;
  }
#undef STAGE

#pragma unroll
  for (int fr = 0; fr < 4; ++fr)
#pragma unroll
    for (int r = 0; r < 4; ++r)
      if (lm == 0) atomicMax(&Mu[wrow + fr * 16 + g4 * 4 + r], mono(rm[fr][r]));

  __syncthreads();   // all appends done
  if (t == 0) bcnt[blockIdx.x] = (lcnt < CPB) ? lcnt : CPB;
}

// ============================ K2b: filtered exact rescore ============================
// block b handles region b; 16 lanes per candidate; filter by final Mu BEFORE any dot.
__global__ __launch_bounds__(256) void rescore_kernel(
    const float* __restrict__ h, const float* __restrict__ table,
    unsigned char* __restrict__ ws) {
  const float* c2 = (const float*)(ws + OFF_C2);
  const unsigned* Mu = (const unsigned*)(ws + OFF_M);
  unsigned long long* best = (unsigned long long*)(ws + OFF_BEST);
  const unsigned* bcnt = (const unsigned*)(ws + OFF_BCNT);
  const uint2* cand = (const uint2*)(ws + OFF_CAND) + (size_t)blockIdx.x * CPB;

  const unsigned count = bcnt[blockIdx.x];
  const int g = threadIdx.x & 15;
  const unsigned grp = threadIdx.x >> 4;   // 16 groups per block

  for (unsigned i = grp; i < count; i += 16) {
    const uint2 e = cand[i];
    const unsigned row = e.x >> 13, code = e.x & 8191u;
    const float sbf = __uint_as_float(e.y);
    if (sbf < demono(Mu[row]) - MARGIN) continue;   // not a contender (uniform per group)
    const float4* hp = (const float4*)(h + (size_t)row * DQ);
    const float4* tp = (const float4*)(table + (size_t)code * DQ);
    float dot = 0.f;
#pragma unroll
    for (int q = 0; q < 4; ++q) {
      float4 a = hp[g * 4 + q], b = tp[g * 4 + q];
      dot = fmaf(a.x, b.x, dot); dot = fmaf(a.y, b.y, dot);
      dot = fmaf(a.z, b.z, dot); dot = fmaf(a.w, b.w, dot);
    }
    dot += __shfl_xor(dot, 1);
    dot += __shfl_xor(dot, 2);
    dot += __shfl_xor(dot, 4);
    dot += __shfl_xor(dot, 8);
    if (g == 0) {
      const float sx = fmaf(2.f, dot, -c2[code]);
      const unsigned long long key =
          ((unsigned long long)mono(sx) << 32) |
          (unsigned long long)(0xFFFFFFFFu - code);
      atomicMax(&best[row], key);   // ties -> smaller code wins (np.argmax)
    }
  }
}

// ============================ fallback two-pass scan (R7, proven) ============================
template<int MODE>
__global__ __launch_bounds__(256, 3) void scan3_kernel(
    const float* __restrict__ h, const float* __restrict__ table,
    unsigned char* __restrict__ ws) {
  const unsigned short* tbf = (const unsigned short*)(ws + OFF_TBF);
  const float* c2 = (const float*)(ws + OFF_C2);
  unsigned* Mu = (unsigned*)(ws + OFF_M);
  unsigned long long* best = (unsigned long long*)(ws + OFF_BEST);
  __shared__ unsigned short bt[2][32 * 256];

  const int t = threadIdx.x, lane = t & 63, wid = t >> 6;
  const int g4 = lane >> 4, lm = lane & 15;
  const int rb = blockIdx.x >> 3, sp = blockIdx.x & 7;
  const int wrow = rb * 128 + wid * 32;
  const int code0 = sp * 1024;

  s16x8 ah[2][8];
#pragma unroll
  for (int fr = 0; fr < 2; ++fr) {
    const float* hp = h + (size_t)(wrow + fr * 16 + lm) * DQ + g4 * 8;
#pragma unroll
    for (int ks = 0; ks < 8; ++ks) {
      float4 a0 = *(const float4*)(hp + ks * 32);
      float4 a1 = *(const float4*)(hp + ks * 32 + 4);
      s16x8 v;
      v[0]=(short)bf_tr(a0.x); v[1]=(short)bf_tr(a0.y);
      v[2]=(short)bf_tr(a0.z); v[3]=(short)bf_tr(a0.w);
      v[4]=(short)bf_tr(a1.x); v[5]=(short)bf_tr(a1.y);
      v[6]=(short)bf_tr(a1.z); v[7]=(short)bf_tr(a1.w);
      ah[fr][ks] = v;
    }
  }

  float rm[2][4];
#pragma unroll
  for (int fr = 0; fr < 2; ++fr)
#pragma unroll
    for (int r = 0; r < 4; ++r) {
      if (MODE == 2) rm[fr][r] = -3.4e38f;
      else           rm[fr][r] = demono(Mu[wrow + fr * 16 + g4 * 4 + r]);
    }

  int psrc[4], pdst[4];
#pragma unroll
  for (int p = 0; p < 4; ++p) {
    const int o = p * 4096 + t * 16;
    const int code = o >> 9, gsw = (o >> 4) & 31;
    const int gsrc = gsw ^ (code & 7);
    psrc[p] = code * 256 + gsrc * 8;
    pdst[p] = p * 2048 + t * 8;
  }
  const unsigned short* sbase = tbf + (size_t)code0 * DQ;

#define STAGE(buf, tilev)                                                     \
  {                                                                           \
    const unsigned short* s0 = sbase + (size_t)(tilev) * 8192;                \
    _Pragma("unroll")                                                         \
    for (int p = 0; p < 4; ++p)                                               \
      __builtin_amdgcn_global_load_lds(                                       \
          (const unsigned int*)(s0 + psrc[p]),                                \
          (unsigned int*)&bt[buf][pdst[p]], 16, 0, 0);                        \
  }

  STAGE(0, 0);
  __syncthreads();
  int cur = 0;

  for (int tile = 0; tile < 32; ++tile) {
    if (tile + 1 < 32) STAGE(cur ^ 1, tile + 1);

    f32x4 acc[2][2];
#pragma unroll
    for (int fr = 0; fr < 2; ++fr)
#pragma unroll
      for (int fc = 0; fc < 2; ++fc) acc[fr][fc] = (f32x4)0.f;

#pragma unroll
    for (int ks = 0; ks < 8; ++ks) {
      const int gb = ks * 4 + g4;
      const int c0 = lm,      gr0 = gb ^ (c0 & 7);
      const int c1 = 16 + lm, gr1 = gb ^ (c1 & 7);
      s16x8 b0 = *(const s16x8*)&bt[cur][c0 * 256 + gr0 * 8];
      s16x8 b1 = *(const s16x8*)&bt[cur][c1 * 256 + gr1 * 8];
      acc[0][0] = mfma16(ah[0][ks], b0, acc[0][0]);
      acc[1][0] = mfma16(ah[1][ks], b0, acc[1][0]);
      acc[0][1] = mfma16(ah[0][ks], b1, acc[0][1]);
      acc[1][1] = mfma16(ah[1][ks], b1, acc[1][1]);
    }

#pragma unroll
    for (int fc = 0; fc < 2; ++fc) {
      const int code_g = code0 + tile * 32 + fc * 16 + lm;
      const float cc = c2[code_g];
#pragma unroll
      for (int fr = 0; fr < 2; ++fr)
#pragma unroll
        for (int r = 0; r < 4; ++r) {
          const float s = fmaf(2.f, acc[fr][fc][r], -cc);
          if (MODE == 2) {
            rm[fr][r] = fmaxf(rm[fr][r], s);
          } else {
            if (s >= rm[fr][r] - MARGIN) {
              const int row_g = wrow + fr * 16 + g4 * 4 + r;
              const float4* hp4 = (const float4*)(h + (size_t)row_g * DQ);
              const float4* tp4 = (const float4*)(table + (size_t)code_g * DQ);
              float dot = 0.f;
#pragma unroll 4
              for (int q = 0; q < 64; ++q) {
                float4 a = hp4[q], bb = tp4[q];
                dot = fmaf(a.x, bb.x, dot); dot = fmaf(a.y, bb.y, dot);
                dot = fmaf(a.z, bb.z, dot); dot = fmaf(a.w, bb.w, dot);
              }
              const float sx = fmaf(2.f, dot, -cc);
              const unsigned long long key =
                  ((unsigned long long)mono(sx) << 32) |
                  (unsigned long long)(0xFFFFFFFFu - (unsigned)code_g);
              atomicMax(&best[row_g], key);
            }
          }
        }
    }

    __syncthreads();
    cur ^= 1;
  }
#undef STAGE

  if (MODE == 2) {
#pragma unroll
    for (int fr = 0; fr < 2; ++fr)
#pragma unroll
      for (int r = 0; r < 4; ++r) {
        float v = rm[fr][r];
        v = fmaxf(v, __shfl_xor(v, 1));
        v = fmaxf(v, __shfl_xor(v, 2));
        v = fmaxf(v, __shfl_xor(v, 4));
        v = fmaxf(v, __shfl_xor(v, 8));
        if (lm == 0) atomicMax(&Mu[wrow + fr * 16 + g4 * 4 + r], mono(v));
      }
  }
}

// ============================ K4: gather ============================
// grid 1024 = 16 rows/block; 16 lanes x 64B per row.
__global__ __launch_bounds__(256) void gather_kernel(
    const float* __restrict__ table, const unsigned char* __restrict__ ws,
    float* __restrict__ out) {
  const unsigned long long* best = (const unsigned long long*)(ws + OFF_BEST);
  const int row = blockIdx.x * 16 + (threadIdx.x >> 4);
  const int part = threadIdx.x & 15;
  const unsigned code = 0xFFFFFFFFu - (unsigned)(best[row] & 0xFFFFFFFFull);
  const float4* src = (const float4*)(table + (size_t)code * DQ + part * 16);
  float4* dst = (float4*)(out + (size_t)row * DQ + part * 16);
#pragma unroll
  for (int q = 0; q < 4; ++q) dst[q] = src[q];
}

// ============================ launch ============================
extern "C" void kernel_launch(void* const* d_in, const int* in_sizes, int n_in,
                              void* d_out, int out_size, void* d_ws, size_t ws_size,
                              hipStream_t stream) {
  const float* x     = (const float*)d_in[0];
  const float* Wm    = (const float*)d_in[1];
  const float* bias  = (const float*)d_in[2];
  const float* table = (const float*)d_in[3];
  float* out = (float*)d_out;
  unsigned char* ws = (unsigned char*)d_ws;

  prep_kernel<<<PB_TBF + PB_C2 + PB_W + PB_INIT, 256, 0, stream>>>(Wm, table, ws);
  h_gemm_kernel<<<512, 256, 0, stream>>>(x, bias, ws, out);    // h lives in d_out

  if (ws_size >= WS_SINGLE) {
    scan7_kernel<<<NSCAN, 256, 0, stream>>>(out, table, ws);   // scan + collect + Mu
    rescore_kernel<<<NSCAN, 256, 0, stream>>>(out, table, ws); // filter + exact rescore
  } else {
    scan3_kernel<2><<<1024, 256, 0, stream>>>(out, table, ws); // two-pass fallback (R7)
    scan3_kernel<3><<<1024, 256, 0, stream>>>(out, table, ws);
  }

  gather_kernel<<<M_TOTAL / 16, 256, 0, stream>>>(table, ws, out);
}